// Round 1
// baseline (939.154 us; speedup 1.0000x reference)
//
#include <hip/hip_runtime.h>
#include <hip/hip_bf16.h>
#include <math.h>

#define DD 2048
#define LOGD 11
#define RBINS 1025
#define KFREQ 128
#define TPB 256
#define POLY_KEEP 1024
#define MICRO_KEEP 512

typedef __bf16 bf16x8 __attribute__((ext_vector_type(8)));
typedef float f32x4 __attribute__((ext_vector_type(4)));
typedef const __attribute__((address_space(1))) void* gas_ptr;
typedef __attribute__((address_space(3))) void* las_ptr;

__device__ __forceinline__ void gl_lds16(const void* g, void* l) {
    __builtin_amdgcn_global_load_lds((gas_ptr)g, (las_ptr)l, 16, 0, 0);
}

// ---------- block reductions (256 threads, 4 waves) ----------
__device__ __forceinline__ void blockReduce2(float& a, float& b, volatile float* sc) {
    for (int o = 32; o; o >>= 1) { a += __shfl_down(a, o); b += __shfl_down(b, o); }
    int w = threadIdx.x >> 6, ln = threadIdx.x & 63;
    if (ln == 0) { sc[w] = a; sc[4 + w] = b; }
    __syncthreads();
    if (threadIdx.x == 0) {
        sc[0] = sc[0] + sc[1] + sc[2] + sc[3];
        sc[4] = sc[4] + sc[5] + sc[6] + sc[7];
    }
    __syncthreads();
    a = sc[0]; b = sc[4];
    __syncthreads();
}

__device__ __forceinline__ int blockReduceSumI(int v, volatile int* sc) {
    for (int o = 32; o; o >>= 1) v += __shfl_down(v, o);
    int w = threadIdx.x >> 6, ln = threadIdx.x & 63;
    if (ln == 0) sc[w] = v;
    __syncthreads();
    if (threadIdx.x == 0) sc[0] = sc[0] + sc[1] + sc[2] + sc[3];
    __syncthreads();
    v = sc[0];
    __syncthreads();
    return v;
}

// ---------- in-LDS 2048-pt complex FFT ----------
__device__ __forceinline__ void fft_core(float* re, float* im, const float2* __restrict__ tw,
                                         int tid, float wsign) {
    __syncthreads();
    for (int i = tid; i < DD; i += TPB) {
        int j = (int)(__brev((unsigned)i) >> (32 - LOGD));
        if (j > i) {
            float tr = re[i]; re[i] = re[j]; re[j] = tr;
            float ti = im[i]; im[i] = im[j]; im[j] = ti;
        }
    }
    int shift = 0;
    for (int half = 1; half < DD; half <<= 1, ++shift) {
        __syncthreads();
        #pragma unroll
        for (int s = 0; s < 4; ++s) {
            int b = tid + s * TPB;                 // butterfly id 0..1023
            int p = b & (half - 1);
            int i0 = ((b >> shift) << (shift + 1)) | p;
            int i1 = i0 + half;
            float2 w = tw[half + p];
            float wy = wsign * w.y;
            float br = re[i1], bi = im[i1];
            float tr = w.x * br - wy * bi;
            float ti = w.x * bi + wy * br;
            float ar = re[i0], ai = im[i0];
            re[i0] = ar + tr; im[i0] = ai + ti;
            re[i1] = ar - tr; im[i1] = ai - ti;
        }
    }
    __syncthreads();
}

// ---------- setup: masks + twiddles ----------
__global__ void k_prep(const float* __restrict__ poly_imp, const float* __restrict__ micro_imp,
                       float* __restrict__ pmask, float* __restrict__ mmask,
                       float2* __restrict__ tw) {
    int d = blockIdx.x * blockDim.x + threadIdx.x;   // 0..2047
    float pv = poly_imp[d], mv = micro_imp[d];
    int rp = 0, rm = 0;
    for (int e = 0; e < DD; ++e) {
        float pe = poly_imp[e];
        float me = micro_imp[e];
        rp += (int)((pe > pv) || (pe == pv && e < d));
        rm += (int)((me > mv) || (me == mv && e < d));
    }
    pmask[d] = (rp < POLY_KEEP) ? 1.f : 0.f;
    mmask[d] = (rm < MICRO_KEEP) ? 1.f : 0.f;
    if (d == 0) {
        tw[0] = make_float2(1.f, 0.f);
    } else {
        int half = 1 << (31 - __clz(d));
        int p = d - half;
        double ang = M_PI * (double)p / (double)half;
        tw[d] = make_float2((float)cos(ang), (float)(-sin(ang)));
    }
}

// ---------- setup: W_res -> bf16 ----------
__global__ void k_wcast(const float* __restrict__ W, __bf16* __restrict__ Wb) {
    int i = (blockIdx.x * blockDim.x + threadIdx.x) * 8;
    float4 a = *(const float4*)(W + i);
    float4 b = *(const float4*)(W + i + 4);
    bf16x8 o;
    o[0] = (__bf16)a.x; o[1] = (__bf16)a.y; o[2] = (__bf16)a.z; o[3] = (__bf16)a.w;
    o[4] = (__bf16)b.x; o[5] = (__bf16)b.y; o[6] = (__bf16)b.z; o[7] = (__bf16)b.w;
    *(bf16x8*)(Wb + i) = o;
}

// ---------- per-row: LN -> FFT -> topk scale -> iFFT -> poly/micro -> LN -> bf16 ----------
__global__ __launch_bounds__(TPB) void k_row(
    const float* __restrict__ x,
    const float* __restrict__ g_in, const float* __restrict__ b_in,
    const float* __restrict__ g_out, const float* __restrict__ b_out,
    const float* __restrict__ gains, const float* __restrict__ spec_bias,
    const float* __restrict__ coeffs,
    const float* __restrict__ mw1, const float* __restrict__ mb1,
    const float* __restrict__ mw2, const float* __restrict__ mb2,
    const float* __restrict__ pmask, const float* __restrict__ mmask,
    const float2* __restrict__ tw,
    __bf16* __restrict__ hf) {

    __shared__ float sRe[DD];
    __shared__ float sIm[DD];
    __shared__ float sMag[RBINS];
    __shared__ float sScale[RBINS];
    __shared__ int   sList[RBINS];
    __shared__ float sRedF[8];
    __shared__ int   sRedI[4];
    __shared__ unsigned sKcnt;

    const int tid = threadIdx.x;
    const int row = blockIdx.x;
    const float* xr = x + (size_t)row * DD;
    const int d0 = tid * 8;

    // ---- LN_in ----
    float xv[8];
    {
        float4 a = *(const float4*)(xr + d0);
        float4 b = *(const float4*)(xr + d0 + 4);
        xv[0] = a.x; xv[1] = a.y; xv[2] = a.z; xv[3] = a.w;
        xv[4] = b.x; xv[5] = b.y; xv[6] = b.z; xv[7] = b.w;
    }
    float s = 0.f, ss = 0.f;
    #pragma unroll
    for (int j = 0; j < 8; ++j) { s += xv[j]; ss += xv[j] * xv[j]; }
    blockReduce2(s, ss, sRedF);
    {
        float mu = s * (1.f / DD);
        float var = ss * (1.f / DD) - mu * mu;
        float rstd = rsqrtf(var + 1e-5f);
        #pragma unroll
        for (int j = 0; j < 8; ++j) {
            int d = d0 + j;
            sRe[d] = (xv[j] - mu) * rstd * g_in[d] + b_in[d];
            sIm[d] = 0.f;
        }
    }

    // ---- forward FFT ----
    fft_core(sRe, sIm, tw, tid, 1.0f);

    // ---- magnitudes^2 for bins 0..1024; zero scale ----
    for (int k = tid; k < RBINS; k += TPB) {
        float r = sRe[k], i = sIm[k];
        sMag[k] = r * r + i * i;
        sScale[k] = 0.f;
    }
    if (tid == 0) sKcnt = 0u;
    __syncthreads();

    // ---- binary search for the 128th largest |X|^2 (float bits, positive) ----
    unsigned lo = 0u, hi = 0x7f800000u;
    for (int it = 0; it < 32 && lo < hi; ++it) {
        unsigned mid = lo + ((hi - lo + 1) >> 1);
        int c = 0;
        for (int k = tid; k < RBINS; k += TPB)
            c += (int)(__float_as_uint(sMag[k]) >= mid);
        c = blockReduceSumI(c, sRedI);
        if (c >= KFREQ) lo = mid; else hi = mid - 1;
    }
    const unsigned V = lo;

    // ---- compact kept candidates, exact ranks (stable tie-break by index) ----
    for (int k = tid; k < RBINS; k += TPB) {
        if (__float_as_uint(sMag[k]) >= V) {
            unsigned p = atomicAdd(&sKcnt, 1u);
            sList[p] = k;
        }
    }
    __syncthreads();
    {
        unsigned kc = sKcnt;
        for (unsigned j = tid; j < kc; j += TPB) {
            int k = sList[j];
            float mk = sMag[k];
            int rank = 0;
            for (int i = 0; i < RBINS; ++i) {
                float mi = sMag[i];
                rank += (int)((mi > mk) || (mi == mk && i < k));
            }
            if (rank < KFREQ) sScale[k] = gains[rank];
        }
    }
    __syncthreads();

    // ---- apply scale + Hermitian extension ----
    for (int k = tid; k <= DD / 2; k += TPB) {
        float sc = sScale[k];
        float r = sRe[k] * sc, i = sIm[k] * sc;
        if (k == 0 || k == DD / 2) i = 0.f;
        sRe[k] = r; sIm[k] = i;
        if (k > 0 && k < DD / 2) { sRe[DD - k] = r; sIm[DD - k] = -i; }
    }
    __syncthreads();

    // ---- inverse FFT ----
    fft_core(sRe, sIm, tw, tid, -1.0f);

    // ---- poly + micro + LN_out, write bf16 ----
    const float c0 = coeffs[0], c1 = coeffs[1], c2 = coeffs[2];
    const float w1 = mw1[0], b1 = mb1[0], w2 = mw2[0], b2 = mb2[0];
    float tv[8];
    s = 0.f; ss = 0.f;
    #pragma unroll
    for (int j = 0; j < 8; ++j) {
        int d = d0 + j;
        float t = sRe[d] * (1.f / DD) + spec_bias[d];
        float xp = t;
        float acc = c0 * xp;
        xp *= t; acc += c1 * xp;
        xp *= t; acc += c2 * xp;
        float tp = (pmask[d] > 0.f) ? acc : t;
        float y = w1 * tp + b1;
        y = y / (1.f + __expf(-y));
        y = w2 * y + b2;
        y = y / (1.f + __expf(-y));
        float tm = (mmask[d] > 0.f) ? y : tp;
        tv[j] = tm; s += tm; ss += tm * tm;
    }
    blockReduce2(s, ss, sRedF);
    {
        float mu = s * (1.f / DD);
        float var = ss * (1.f / DD) - mu * mu;
        float rstd = rsqrtf(var + 1e-5f);
        bf16x8 o;
        #pragma unroll
        for (int j = 0; j < 8; ++j) {
            int d = d0 + j;
            o[j] = (__bf16)((tv[j] - mu) * rstd * g_out[d] + b_out[d]);
        }
        *(bf16x8*)(hf + (size_t)row * DD + d0) = o;
    }
}

// ---------- GEMM: out = x + gate*(Hf @ W^T + b_res), 128x128 tile, bf16 MFMA ----------
__global__ __launch_bounds__(TPB) void k_gemm(
    const __bf16* __restrict__ A,   // [8192, 2048] bf16
    const __bf16* __restrict__ Bt,  // [2048(e), 2048(d)] bf16 (= W_res as stored)
    const float* __restrict__ x,
    const float* __restrict__ b_res,
    const float* __restrict__ gate_p,
    float* __restrict__ out) {

    __shared__ __bf16 As[128 * 32];
    __shared__ __bf16 Bs[128 * 32];

    const int tid = threadIdx.x;
    const int lane = tid & 63;
    const int w = tid >> 6;
    const int m0 = blockIdx.y * 128;
    const int n0 = blockIdx.x * 128;
    const int wm = (w >> 1) * 64;
    const int wn = (w & 1) * 64;
    const int K = DD;

    f32x4 acc[4][4] = {};

    const int l15 = lane & 15;
    const int l4 = lane >> 4;

    for (int k0 = 0; k0 < K; k0 += 32) {
        __syncthreads();
        #pragma unroll
        for (int sgl = 0; sgl < 2; ++sgl) {
            int qb = sgl * 256 + w * 64;       // wave-uniform chunk base
            int q = qb + lane;                 // per-lane chunk id (0..511)
            const __bf16* ga = A + (size_t)(m0 + (q >> 2)) * K + k0 + (q & 3) * 8;
            gl_lds16(ga, &As[qb * 8]);
            const __bf16* gb = Bt + (size_t)(n0 + (q >> 2)) * K + k0 + (q & 3) * 8;
            gl_lds16(gb, &Bs[qb * 8]);
        }
        __syncthreads();

        bf16x8 af[4], bfr[4];
        #pragma unroll
        for (int i = 0; i < 4; ++i) {
            af[i]  = *(const bf16x8*)&As[(wm + i * 16 + l15) * 32 + l4 * 8];
            bfr[i] = *(const bf16x8*)&Bs[(wn + i * 16 + l15) * 32 + l4 * 8];
        }
        #pragma unroll
        for (int i = 0; i < 4; ++i)
            #pragma unroll
            for (int j = 0; j < 4; ++j)
                acc[i][j] = __builtin_amdgcn_mfma_f32_16x16x32_bf16(af[i], bfr[j], acc[i][j], 0, 0, 0);
    }

    const float gate = gate_p[0];
    #pragma unroll
    for (int i = 0; i < 4; ++i) {
        int mbase = m0 + wm + i * 16 + l4 * 4;
        #pragma unroll
        for (int j = 0; j < 4; ++j) {
            int n = n0 + wn + j * 16 + l15;
            float br = b_res[n];
            #pragma unroll
            for (int r = 0; r < 4; ++r) {
                size_t off = (size_t)(mbase + r) * DD + n;
                out[off] = x[off] + gate * (acc[i][j][r] + br);
            }
        }
    }
}

extern "C" void kernel_launch(void* const* d_in, const int* in_sizes, int n_in,
                              void* d_out, int out_size, void* d_ws, size_t ws_size,
                              hipStream_t stream) {
    const float* x         = (const float*)d_in[0];
    const float* ln_in_g   = (const float*)d_in[1];
    const float* ln_in_b   = (const float*)d_in[2];
    const float* ln_out_g  = (const float*)d_in[3];
    const float* ln_out_b  = (const float*)d_in[4];
    const float* spec_gain = (const float*)d_in[5];
    const float* spec_bias = (const float*)d_in[6];
    const float* poly_c    = (const float*)d_in[7];
    const float* poly_imp  = (const float*)d_in[8];
    const float* micro_imp = (const float*)d_in[9];
    const float* mw1       = (const float*)d_in[10];
    const float* mb1       = (const float*)d_in[11];
    const float* mw2       = (const float*)d_in[12];
    const float* mb2       = (const float*)d_in[13];
    const float* W_res     = (const float*)d_in[14];
    const float* b_res     = (const float*)d_in[15];
    const float* gate      = (const float*)d_in[16];
    float* out = (float*)d_out;

    char* ws = (char*)d_ws;
    __bf16* hf    = (__bf16*)(ws);                       // 8192*2048*2 = 32 MiB
    __bf16* Wb    = (__bf16*)(ws + 33554432);            // 8 MiB
    float2* tw    = (float2*)(ws + 41943040);            // 16 KiB
    float*  pmask = (float*)(ws + 41959424);             // 8 KiB
    float*  mmask = (float*)(ws + 41967616);             // 8 KiB

    k_prep<<<dim3(8), dim3(TPB), 0, stream>>>(poly_imp, micro_imp, pmask, mmask, tw);
    k_wcast<<<dim3(2048), dim3(TPB), 0, stream>>>(W_res, Wb);
    k_row<<<dim3(8192), dim3(TPB), 0, stream>>>(x, ln_in_g, ln_in_b, ln_out_g, ln_out_b,
                                                spec_gain, spec_bias, poly_c,
                                                mw1, mb1, mw2, mb2,
                                                pmask, mmask, tw, hf);
    k_gemm<<<dim3(16, 64), dim3(TPB), 0, stream>>>(hf, Wb, x, b_res, gate, out);
}

// Round 2
// 540.588 us; speedup vs baseline: 1.7373x; 1.7373x over previous
//
#include <hip/hip_runtime.h>
#include <hip/hip_bf16.h>
#include <math.h>

#define DD 2048
#define MM 1024
#define RBINS 1025
#define KFREQ 128
#define TPB 256
#define POLY_KEEP 1024
#define MICRO_KEEP 512

typedef __bf16 bf16x8 __attribute__((ext_vector_type(8)));
typedef float f32x4 __attribute__((ext_vector_type(4)));
typedef const __attribute__((address_space(1))) void* gas_ptr;
typedef __attribute__((address_space(3))) void* las_ptr;

__device__ __forceinline__ void gl_lds16(const void* g, void* l) {
    __builtin_amdgcn_global_load_lds((gas_ptr)g, (las_ptr)l, 16, 0, 0);
}

__device__ __forceinline__ int SWZ(int i) { return i ^ ((i >> 4) & 15); }
__device__ __forceinline__ int BREV10(int i) { return (int)(__brev((unsigned)i) >> 22); }

// ---------- block reductions (256 threads, 4 waves) ----------
__device__ __forceinline__ void blockReduce2(float& a, float& b, volatile float* sc) {
    for (int o = 32; o; o >>= 1) { a += __shfl_down(a, o); b += __shfl_down(b, o); }
    int w = threadIdx.x >> 6, ln = threadIdx.x & 63;
    if (ln == 0) { sc[w] = a; sc[4 + w] = b; }
    __syncthreads();
    if (threadIdx.x == 0) {
        sc[0] = sc[0] + sc[1] + sc[2] + sc[3];
        sc[4] = sc[4] + sc[5] + sc[6] + sc[7];
    }
    __syncthreads();
    a = sc[0]; b = sc[4];
    __syncthreads();
}

// ---------- in-LDS 1024-pt complex FFT: 5 fused radix-4 stages, in-place,
//            input must be in bit-reversed order; output natural order ----------
__device__ __forceinline__ void fft5(float2* Z, const float2* __restrict__ tw,
                                     int tid, float wsign) {
    #pragma unroll
    for (int s = 0; s < 5; ++s) {
        const int h = 1 << (2 * s);
        __syncthreads();
        int g, p;
        if (s == 1) { g = tid & 63; p = tid >> 6; }          // transposed map: bank-friendly
        else { p = tid & (h - 1); g = tid >> (2 * s); }
        const int i0 = g * 4 * h + p;
        float2 T1 = tw[h + p];
        float2 T2 = tw[2 * h + p];
        float2 T3 = tw[3 * h + p];
        const float t1y = wsign * T1.y, t2y = wsign * T2.y, t3y = wsign * T3.y;
        float2 z0 = Z[SWZ(i0)];
        float2 z1 = Z[SWZ(i0 + h)];
        float2 z2 = Z[SWZ(i0 + 2 * h)];
        float2 z3 = Z[SWZ(i0 + 3 * h)];
        // pass 1 (half = h), twiddle T1 for both pairs
        float ar = T1.x * z1.x - t1y * z1.y, ai = T1.x * z1.y + t1y * z1.x;
        float br = T1.x * z3.x - t1y * z3.y, bi = T1.x * z3.y + t1y * z3.x;
        float u0r = z0.x + ar, u0i = z0.y + ai;
        float u1r = z0.x - ar, u1i = z0.y - ai;
        float u2r = z2.x + br, u2i = z2.y + bi;
        float u3r = z2.x - br, u3i = z2.y - bi;
        // pass 2 (half = 2h), twiddles T2 (pos p) and T3 (pos p+h)
        ar = T2.x * u2r - t2y * u2i; ai = T2.x * u2i + t2y * u2r;
        br = T3.x * u3r - t3y * u3i; bi = T3.x * u3i + t3y * u3r;
        Z[SWZ(i0)]         = make_float2(u0r + ar, u0i + ai);
        Z[SWZ(i0 + h)]     = make_float2(u1r + br, u1i + bi);
        Z[SWZ(i0 + 2 * h)] = make_float2(u0r - ar, u0i - ai);
        Z[SWZ(i0 + 3 * h)] = make_float2(u1r - br, u1i - bi);
    }
    __syncthreads();
}

// ---------- setup: masks + twiddles ----------
__global__ void k_prep(const float* __restrict__ poly_imp, const float* __restrict__ micro_imp,
                       float* __restrict__ pmask, float* __restrict__ mmask,
                       float2* __restrict__ tw) {
    int d = blockIdx.x * blockDim.x + threadIdx.x;   // 0..2047
    float pv = poly_imp[d], mv = micro_imp[d];
    int rp = 0, rm = 0;
    for (int e = 0; e < DD; ++e) {
        float pe = poly_imp[e];
        float me = micro_imp[e];
        rp += (int)((pe > pv) || (pe == pv && e < d));
        rm += (int)((me > mv) || (me == mv && e < d));
    }
    pmask[d] = (rp < POLY_KEEP) ? 1.f : 0.f;
    mmask[d] = (rm < MICRO_KEEP) ? 1.f : 0.f;
    if (d == 0) {
        tw[0] = make_float2(1.f, 0.f);
    } else {
        int half = 1 << (31 - __clz(d));
        int p = d - half;
        double ang = M_PI * (double)p / (double)half;
        tw[d] = make_float2((float)cos(ang), (float)(-sin(ang)));
    }
}

// ---------- setup: W_res -> bf16 ----------
__global__ void k_wcast(const float* __restrict__ W, __bf16* __restrict__ Wb) {
    int i = (blockIdx.x * blockDim.x + threadIdx.x) * 8;
    float4 a = *(const float4*)(W + i);
    float4 b = *(const float4*)(W + i + 4);
    bf16x8 o;
    o[0] = (__bf16)a.x; o[1] = (__bf16)a.y; o[2] = (__bf16)a.z; o[3] = (__bf16)a.w;
    o[4] = (__bf16)b.x; o[5] = (__bf16)b.y; o[6] = (__bf16)b.z; o[7] = (__bf16)b.w;
    *(bf16x8*)(Wb + i) = o;
}

// ---------- per-row: LN -> rfft(via 1024 cFFT) -> topk scale -> irfft -> poly/micro -> LN -> bf16 ----------
__global__ __launch_bounds__(TPB) void k_row(
    const float* __restrict__ x,
    const float* __restrict__ g_in, const float* __restrict__ b_in,
    const float* __restrict__ g_out, const float* __restrict__ b_out,
    const float* __restrict__ gains, const float* __restrict__ spec_bias,
    const float* __restrict__ coeffs,
    const float* __restrict__ mw1, const float* __restrict__ mb1,
    const float* __restrict__ mw2, const float* __restrict__ mb2,
    const float* __restrict__ pmask, const float* __restrict__ mmask,
    const float2* __restrict__ tw,
    __bf16* __restrict__ hf) {

    __shared__ float2 sZ[MM];                       // 8 KB, swizzled; aliased by cand list
    __shared__ float2 sX[RBINS];                    // 8.2 KB
    __shared__ __align__(16) float sMag[RBINS + 3]; // 4.1 KB
    __shared__ float sScale[RBINS];                 // 4.1 KB
    __shared__ float sRedF[8];
    __shared__ int   sRedI[4];
    __shared__ unsigned sKcnt;

    int*   sCand = (int*)sZ;                        // alias: valid between X-pass and pack
    float* sCMag = (float*)sZ + MM;

    const int tid = threadIdx.x;
    const int row = blockIdx.x;
    const float* xr = x + (size_t)row * DD;
    const int d0 = tid * 8;

    // ---- LN_in ----
    float xv[8];
    {
        float4 a = *(const float4*)(xr + d0);
        float4 b = *(const float4*)(xr + d0 + 4);
        xv[0] = a.x; xv[1] = a.y; xv[2] = a.z; xv[3] = a.w;
        xv[4] = b.x; xv[5] = b.y; xv[6] = b.z; xv[7] = b.w;
    }
    float s = 0.f, ss = 0.f;
    #pragma unroll
    for (int j = 0; j < 8; ++j) { s += xv[j]; ss += xv[j] * xv[j]; }
    blockReduce2(s, ss, sRedF);
    {
        float mu = s * (1.f / DD);
        float var = ss * (1.f / DD) - mu * mu;
        float rstd = rsqrtf(var + 1e-5f);
        // pack z[n] = h[2n] + i h[2n+1], scatter bit-reversed (+swizzle)
        #pragma unroll
        for (int j = 0; j < 4; ++j) {
            int n = 4 * tid + j;
            int d = d0 + 2 * j;
            float re = (xv[2 * j]     - mu) * rstd * g_in[d]     + b_in[d];
            float im = (xv[2 * j + 1] - mu) * rstd * g_in[d + 1] + b_in[d + 1];
            sZ[SWZ(BREV10(n))] = make_float2(re, im);
        }
    }

    // ---- forward 1024-pt complex FFT ----
    fft5(sZ, tw, tid, 1.0f);

    // ---- unpack to rfft spectrum X[0..1024], mags, zero scales ----
    #pragma unroll
    for (int j = 0; j < 4; ++j) {
        int k = tid + 256 * j;
        float2 a = sZ[SWZ(k)];
        float2 b = sZ[SWZ((MM - k) & (MM - 1))];
        float xer = 0.5f * (a.x + b.x), xei = 0.5f * (a.y - b.y);
        float xor_ = 0.5f * (a.y + b.y), xoi = 0.5f * (b.x - a.x);
        float2 w = tw[MM + k];                       // e^{-i pi k / 1024}
        float Xr = xer + w.x * xor_ - w.y * xoi;
        float Xi = xei + w.x * xoi + w.y * xor_;
        sX[k] = make_float2(Xr, Xi);
        sMag[k] = Xr * Xr + Xi * Xi;
        sScale[k] = 0.f;
    }
    if (tid == 0) {
        float2 z0 = sZ[SWZ(0)];
        float xn = z0.x - z0.y;                      // X[1024] = Xe[0] - Xo[0]
        sX[MM] = make_float2(xn, 0.f);
        sMag[MM] = xn * xn;
        sScale[MM] = 0.f;
        sKcnt = 0u;
    }
    __syncthreads();

    // ---- mags to registers ----
    float4 mvv = *(const float4*)&sMag[tid * 4];
    unsigned um0 = __float_as_uint(mvv.x), um1 = __float_as_uint(mvv.y);
    unsigned um2 = __float_as_uint(mvv.z), um3 = __float_as_uint(mvv.w);
    unsigned xtra = (tid == 0) ? __float_as_uint(sMag[MM]) : 0u;

    // ---- binary search for 128th largest |X|^2 (float bits) ----
    unsigned lo = 0u, hi = 0x7f800000u;
    for (int it = 0; it < 32 && lo < hi; ++it) {
        unsigned mid = lo + ((hi - lo + 1) >> 1);
        int c = (int)(um0 >= mid) + (int)(um1 >= mid) + (int)(um2 >= mid)
              + (int)(um3 >= mid) + (int)(xtra >= mid);
        for (int o = 32; o; o >>= 1) c += __shfl_down(c, o);
        if ((tid & 63) == 0) sRedI[tid >> 6] = c;
        __syncthreads();
        c = sRedI[0] + sRedI[1] + sRedI[2] + sRedI[3];
        if (c >= KFREQ) lo = mid; else hi = mid - 1;
        __syncthreads();
    }
    const unsigned V = lo;

    // ---- compact candidates into aliased sZ region ----
    {
        unsigned m[4] = {um0, um1, um2, um3};
        #pragma unroll
        for (int j = 0; j < 4; ++j) {
            if (m[j] >= V) {
                unsigned pos = atomicAdd(&sKcnt, 1u);
                if (pos < 1024u) { sCand[pos] = tid * 4 + j; sCMag[pos] = __uint_as_float(m[j]); }
            }
        }
        if (xtra >= V) {
            unsigned pos = atomicAdd(&sKcnt, 1u);
            if (pos < 1024u) { sCand[pos] = MM; sCMag[pos] = __uint_as_float(xtra); }
        }
    }
    __syncthreads();

    // ---- exact ranks among candidates only (broadcast reads) ----
    {
        int kc = (int)min(sKcnt, 1024u);
        for (int j = tid; j < kc; j += TPB) {
            int kb = sCand[j]; float mk = sCMag[j];
            int r = 0;
            for (int i = 0; i < kc; ++i) {
                float mi = sCMag[i]; int bi2 = sCand[i];
                r += (int)((mi > mk) || (mi == mk && bi2 < kb));
            }
            if (r < KFREQ) sScale[kb] = gains[r];
        }
    }
    __syncthreads();

    // ---- pack scaled Hermitian spectrum into Z' (bit-reversed scatter), overwrites sZ ----
    #pragma unroll
    for (int j = 0; j < 4; ++j) {
        int k = tid + 256 * j;
        float2 Xk = sX[k];      float sk = sScale[k];
        float2 Xp = sX[MM - k]; float sp = sScale[MM - k];
        float Yr = sk * Xk.x,  Yi = sk * Xk.y;
        float Ycr = sp * Xp.x, Yci = -sp * Xp.y;     // conj(Y[M-k])
        float yer = 0.5f * (Yr + Ycr), yei = 0.5f * (Yi + Yci);
        float tr  = 0.5f * (Yr - Ycr), ti  = 0.5f * (Yi - Yci);
        float2 w = tw[MM + k];                       // conj(w) = e^{+i pi k/1024}
        float yor = tr * w.x + ti * w.y;             // (tr,ti) * conj(w)
        float yoi = ti * w.x - tr * w.y;
        sZ[SWZ(BREV10(k))] = make_float2(yer - yoi, yei + yor);  // Ye + i*Yo
    }

    // ---- inverse 1024-pt complex FFT ----
    fft5(sZ, tw, tid, -1.0f);

    // ---- poly + micro + LN_out, write bf16 ----
    float2 zy[4];
    #pragma unroll
    for (int j = 0; j < 4; ++j) zy[j] = sZ[SWZ(4 * tid + j)];

    const float c0 = coeffs[0], c1 = coeffs[1], c2 = coeffs[2];
    const float w1 = mw1[0], b1 = mb1[0], w2 = mw2[0], b2 = mb2[0];
    float tv[8];
    s = 0.f; ss = 0.f;
    #pragma unroll
    for (int j = 0; j < 8; ++j) {
        int d = d0 + j;
        float v = (j & 1) ? zy[j >> 1].y : zy[j >> 1].x;
        float t = v * (1.f / MM) + spec_bias[d];
        float xp = t;
        float acc = c0 * xp;
        xp *= t; acc += c1 * xp;
        xp *= t; acc += c2 * xp;
        float tp = (pmask[d] > 0.f) ? acc : t;
        float y = w1 * tp + b1;
        y = y / (1.f + __expf(-y));
        y = w2 * y + b2;
        y = y / (1.f + __expf(-y));
        float tm = (mmask[d] > 0.f) ? y : tp;
        tv[j] = tm; s += tm; ss += tm * tm;
    }
    blockReduce2(s, ss, sRedF);
    {
        float mu = s * (1.f / DD);
        float var = ss * (1.f / DD) - mu * mu;
        float rstd = rsqrtf(var + 1e-5f);
        bf16x8 o;
        #pragma unroll
        for (int j = 0; j < 8; ++j) {
            int d = d0 + j;
            o[j] = (__bf16)((tv[j] - mu) * rstd * g_out[d] + b_out[d]);
        }
        *(bf16x8*)(hf + (size_t)row * DD + d0) = o;
    }
}

// ---------- GEMM: out = x + gate*(Hf @ W^T + b_res), 128x128 tile, bf16 MFMA ----------
__global__ __launch_bounds__(TPB) void k_gemm(
    const __bf16* __restrict__ A,   // [8192, 2048] bf16
    const __bf16* __restrict__ Bt,  // [2048(e), 2048(d)] bf16 (= W_res as stored)
    const float* __restrict__ x,
    const float* __restrict__ b_res,
    const float* __restrict__ gate_p,
    float* __restrict__ out) {

    __shared__ __bf16 As[128 * 32];
    __shared__ __bf16 Bs[128 * 32];

    const int tid = threadIdx.x;
    const int lane = tid & 63;
    const int w = tid >> 6;
    const int m0 = blockIdx.y * 128;
    const int n0 = blockIdx.x * 128;
    const int wm = (w >> 1) * 64;
    const int wn = (w & 1) * 64;
    const int K = DD;

    f32x4 acc[4][4] = {};

    const int l15 = lane & 15;
    const int l4 = lane >> 4;

    for (int k0 = 0; k0 < K; k0 += 32) {
        __syncthreads();
        #pragma unroll
        for (int sgl = 0; sgl < 2; ++sgl) {
            int qb = sgl * 256 + w * 64;       // wave-uniform chunk base
            int q = qb + lane;                 // per-lane chunk id (0..511)
            const __bf16* ga = A + (size_t)(m0 + (q >> 2)) * K + k0 + (q & 3) * 8;
            gl_lds16(ga, &As[qb * 8]);
            const __bf16* gb = Bt + (size_t)(n0 + (q >> 2)) * K + k0 + (q & 3) * 8;
            gl_lds16(gb, &Bs[qb * 8]);
        }
        __syncthreads();

        bf16x8 af[4], bfr[4];
        #pragma unroll
        for (int i = 0; i < 4; ++i) {
            af[i]  = *(const bf16x8*)&As[(wm + i * 16 + l15) * 32 + l4 * 8];
            bfr[i] = *(const bf16x8*)&Bs[(wn + i * 16 + l15) * 32 + l4 * 8];
        }
        #pragma unroll
        for (int i = 0; i < 4; ++i)
            #pragma unroll
            for (int j = 0; j < 4; ++j)
                acc[i][j] = __builtin_amdgcn_mfma_f32_16x16x32_bf16(af[i], bfr[j], acc[i][j], 0, 0, 0);
    }

    const float gate = gate_p[0];
    #pragma unroll
    for (int i = 0; i < 4; ++i) {
        int mbase = m0 + wm + i * 16 + l4 * 4;
        #pragma unroll
        for (int j = 0; j < 4; ++j) {
            int n = n0 + wn + j * 16 + l15;
            float br = b_res[n];
            #pragma unroll
            for (int r = 0; r < 4; ++r) {
                size_t off = (size_t)(mbase + r) * DD + n;
                out[off] = x[off] + gate * (acc[i][j][r] + br);
            }
        }
    }
}

extern "C" void kernel_launch(void* const* d_in, const int* in_sizes, int n_in,
                              void* d_out, int out_size, void* d_ws, size_t ws_size,
                              hipStream_t stream) {
    const float* x         = (const float*)d_in[0];
    const float* ln_in_g   = (const float*)d_in[1];
    const float* ln_in_b   = (const float*)d_in[2];
    const float* ln_out_g  = (const float*)d_in[3];
    const float* ln_out_b  = (const float*)d_in[4];
    const float* spec_gain = (const float*)d_in[5];
    const float* spec_bias = (const float*)d_in[6];
    const float* poly_c    = (const float*)d_in[7];
    const float* poly_imp  = (const float*)d_in[8];
    const float* micro_imp = (const float*)d_in[9];
    const float* mw1       = (const float*)d_in[10];
    const float* mb1       = (const float*)d_in[11];
    const float* mw2       = (const float*)d_in[12];
    const float* mb2       = (const float*)d_in[13];
    const float* W_res     = (const float*)d_in[14];
    const float* b_res     = (const float*)d_in[15];
    const float* gate      = (const float*)d_in[16];
    float* out = (float*)d_out;

    char* ws = (char*)d_ws;
    __bf16* hf    = (__bf16*)(ws);                       // 8192*2048*2 = 32 MiB
    __bf16* Wb    = (__bf16*)(ws + 33554432);            // 8 MiB
    float2* tw    = (float2*)(ws + 41943040);            // 16 KiB
    float*  pmask = (float*)(ws + 41959424);             // 8 KiB
    float*  mmask = (float*)(ws + 41967616);             // 8 KiB

    k_prep<<<dim3(8), dim3(TPB), 0, stream>>>(poly_imp, micro_imp, pmask, mmask, tw);
    k_wcast<<<dim3(2048), dim3(TPB), 0, stream>>>(W_res, Wb);
    k_row<<<dim3(8192), dim3(TPB), 0, stream>>>(x, ln_in_g, ln_in_b, ln_out_g, ln_out_b,
                                                spec_gain, spec_bias, poly_c,
                                                mw1, mb1, mw2, mb2,
                                                pmask, mmask, tw, hf);
    k_gemm<<<dim3(16, 64), dim3(TPB), 0, stream>>>(hf, Wb, x, b_res, gate, out);
}

// Round 3
// 505.159 us; speedup vs baseline: 1.8591x; 1.0701x over previous
//
#include <hip/hip_runtime.h>
#include <hip/hip_bf16.h>
#include <math.h>

#define DD 2048
#define MM 1024
#define RBINS 1025
#define KFREQ 128
#define TPB 256
#define POLY_KEEP 1024
#define MICRO_KEEP 512
#define BK 64
#define NT (DD / BK)

typedef __bf16 bf16x8 __attribute__((ext_vector_type(8)));
typedef float f32x4 __attribute__((ext_vector_type(4)));
typedef const __attribute__((address_space(1))) void* gas_ptr;
typedef __attribute__((address_space(3))) void* las_ptr;

__device__ __forceinline__ void gl_lds16(const void* g, void* l) {
    __builtin_amdgcn_global_load_lds((gas_ptr)g, (las_ptr)l, 16, 0, 0);
}

__device__ __forceinline__ int SWZ(int i) { return i ^ ((i >> 4) & 15); }
__device__ __forceinline__ int BREV10(int i) { return (int)(__brev((unsigned)i) >> 22); }

// ---------- block reductions (256 threads, 4 waves) ----------
__device__ __forceinline__ void blockReduce2(float& a, float& b, volatile float* sc) {
    for (int o = 32; o; o >>= 1) { a += __shfl_down(a, o); b += __shfl_down(b, o); }
    int w = threadIdx.x >> 6, ln = threadIdx.x & 63;
    if (ln == 0) { sc[w] = a; sc[4 + w] = b; }
    __syncthreads();
    if (threadIdx.x == 0) {
        sc[0] = sc[0] + sc[1] + sc[2] + sc[3];
        sc[4] = sc[4] + sc[5] + sc[6] + sc[7];
    }
    __syncthreads();
    a = sc[0]; b = sc[4];
    __syncthreads();
}

// ---------- in-LDS 1024-pt complex FFT: 5 fused radix-4 stages ----------
__device__ __forceinline__ void fft5(float2* Z, const float2* __restrict__ tw,
                                     int tid, float wsign) {
    #pragma unroll
    for (int s = 0; s < 5; ++s) {
        const int h = 1 << (2 * s);
        __syncthreads();
        int g, p;
        if (s == 1) { g = tid & 63; p = tid >> 6; }
        else { p = tid & (h - 1); g = tid >> (2 * s); }
        const int i0 = g * 4 * h + p;
        float2 T1 = tw[h + p];
        float2 T2 = tw[2 * h + p];
        float2 T3 = tw[3 * h + p];
        const float t1y = wsign * T1.y, t2y = wsign * T2.y, t3y = wsign * T3.y;
        float2 z0 = Z[SWZ(i0)];
        float2 z1 = Z[SWZ(i0 + h)];
        float2 z2 = Z[SWZ(i0 + 2 * h)];
        float2 z3 = Z[SWZ(i0 + 3 * h)];
        float ar = T1.x * z1.x - t1y * z1.y, ai = T1.x * z1.y + t1y * z1.x;
        float br = T1.x * z3.x - t1y * z3.y, bi = T1.x * z3.y + t1y * z3.x;
        float u0r = z0.x + ar, u0i = z0.y + ai;
        float u1r = z0.x - ar, u1i = z0.y - ai;
        float u2r = z2.x + br, u2i = z2.y + bi;
        float u3r = z2.x - br, u3i = z2.y - bi;
        ar = T2.x * u2r - t2y * u2i; ai = T2.x * u2i + t2y * u2r;
        br = T3.x * u3r - t3y * u3i; bi = T3.x * u3i + t3y * u3r;
        Z[SWZ(i0)]         = make_float2(u0r + ar, u0i + ai);
        Z[SWZ(i0 + h)]     = make_float2(u1r + br, u1i + bi);
        Z[SWZ(i0 + 2 * h)] = make_float2(u0r - ar, u0i - ai);
        Z[SWZ(i0 + 3 * h)] = make_float2(u1r - br, u1i - bi);
    }
    __syncthreads();
}

// ---------- setup: masks + twiddles ----------
__global__ void k_prep(const float* __restrict__ poly_imp, const float* __restrict__ micro_imp,
                       float* __restrict__ pmask, float* __restrict__ mmask,
                       float2* __restrict__ tw) {
    int d = blockIdx.x * blockDim.x + threadIdx.x;
    float pv = poly_imp[d], mv = micro_imp[d];
    int rp = 0, rm = 0;
    for (int e = 0; e < DD; ++e) {
        float pe = poly_imp[e];
        float me = micro_imp[e];
        rp += (int)((pe > pv) || (pe == pv && e < d));
        rm += (int)((me > mv) || (me == mv && e < d));
    }
    pmask[d] = (rp < POLY_KEEP) ? 1.f : 0.f;
    mmask[d] = (rm < MICRO_KEEP) ? 1.f : 0.f;
    if (d == 0) {
        tw[0] = make_float2(1.f, 0.f);
    } else {
        int half = 1 << (31 - __clz(d));
        int p = d - half;
        double ang = M_PI * (double)p / (double)half;
        tw[d] = make_float2((float)cos(ang), (float)(-sin(ang)));
    }
}

// ---------- setup: W_res -> bf16 ----------
__global__ void k_wcast(const float* __restrict__ W, __bf16* __restrict__ Wb) {
    int i = (blockIdx.x * blockDim.x + threadIdx.x) * 8;
    float4 a = *(const float4*)(W + i);
    float4 b = *(const float4*)(W + i + 4);
    bf16x8 o;
    o[0] = (__bf16)a.x; o[1] = (__bf16)a.y; o[2] = (__bf16)a.z; o[3] = (__bf16)a.w;
    o[4] = (__bf16)b.x; o[5] = (__bf16)b.y; o[6] = (__bf16)b.z; o[7] = (__bf16)b.w;
    *(bf16x8*)(Wb + i) = o;
}

// ---------- per-row: LN -> rfft -> topk scale -> irfft -> poly/micro -> LN -> bf16 ----------
__global__ __launch_bounds__(TPB) void k_row(
    const float* __restrict__ x,
    const float* __restrict__ g_in, const float* __restrict__ b_in,
    const float* __restrict__ g_out, const float* __restrict__ b_out,
    const float* __restrict__ gains, const float* __restrict__ spec_bias,
    const float* __restrict__ coeffs,
    const float* __restrict__ mw1, const float* __restrict__ mb1,
    const float* __restrict__ mw2, const float* __restrict__ mb2,
    const float* __restrict__ pmask, const float* __restrict__ mmask,
    const float2* __restrict__ tw,
    __bf16* __restrict__ hf) {

    __shared__ float2 sZ[MM];
    __shared__ float2 sX[RBINS];
    __shared__ __align__(16) float sMag[RBINS + 3];
    __shared__ float sScale[RBINS];
    __shared__ float sRedF[8];
    __shared__ int   sRedI[4];
    __shared__ unsigned sKcnt;

    int*   sCand = (int*)sZ;
    float* sCMag = (float*)sZ + MM;

    const int tid = threadIdx.x;
    const int row = blockIdx.x;
    const float* xr = x + (size_t)row * DD;
    const int d0 = tid * 8;

    float xv[8];
    {
        float4 a = *(const float4*)(xr + d0);
        float4 b = *(const float4*)(xr + d0 + 4);
        xv[0] = a.x; xv[1] = a.y; xv[2] = a.z; xv[3] = a.w;
        xv[4] = b.x; xv[5] = b.y; xv[6] = b.z; xv[7] = b.w;
    }
    float s = 0.f, ss = 0.f;
    #pragma unroll
    for (int j = 0; j < 8; ++j) { s += xv[j]; ss += xv[j] * xv[j]; }
    blockReduce2(s, ss, sRedF);
    {
        float mu = s * (1.f / DD);
        float var = ss * (1.f / DD) - mu * mu;
        float rstd = rsqrtf(var + 1e-5f);
        #pragma unroll
        for (int j = 0; j < 4; ++j) {
            int n = 4 * tid + j;
            int d = d0 + 2 * j;
            float re = (xv[2 * j]     - mu) * rstd * g_in[d]     + b_in[d];
            float im = (xv[2 * j + 1] - mu) * rstd * g_in[d + 1] + b_in[d + 1];
            sZ[SWZ(BREV10(n))] = make_float2(re, im);
        }
    }

    fft5(sZ, tw, tid, 1.0f);

    #pragma unroll
    for (int j = 0; j < 4; ++j) {
        int k = tid + 256 * j;
        float2 a = sZ[SWZ(k)];
        float2 b = sZ[SWZ((MM - k) & (MM - 1))];
        float xer = 0.5f * (a.x + b.x), xei = 0.5f * (a.y - b.y);
        float xor_ = 0.5f * (a.y + b.y), xoi = 0.5f * (b.x - a.x);
        float2 w = tw[MM + k];
        float Xr = xer + w.x * xor_ - w.y * xoi;
        float Xi = xei + w.x * xoi + w.y * xor_;
        sX[k] = make_float2(Xr, Xi);
        sMag[k] = Xr * Xr + Xi * Xi;
        sScale[k] = 0.f;
    }
    if (tid == 0) {
        float2 z0 = sZ[SWZ(0)];
        float xn = z0.x - z0.y;
        sX[MM] = make_float2(xn, 0.f);
        sMag[MM] = xn * xn;
        sScale[MM] = 0.f;
        sKcnt = 0u;
    }
    __syncthreads();

    float4 mvv = *(const float4*)&sMag[tid * 4];
    unsigned um0 = __float_as_uint(mvv.x), um1 = __float_as_uint(mvv.y);
    unsigned um2 = __float_as_uint(mvv.z), um3 = __float_as_uint(mvv.w);
    unsigned xtra = (tid == 0) ? __float_as_uint(sMag[MM]) : 0u;

    unsigned lo = 0u, hi = 0x7f800000u;
    for (int it = 0; it < 32 && lo < hi; ++it) {
        unsigned mid = lo + ((hi - lo + 1) >> 1);
        int c = (int)(um0 >= mid) + (int)(um1 >= mid) + (int)(um2 >= mid)
              + (int)(um3 >= mid) + (int)(xtra >= mid);
        for (int o = 32; o; o >>= 1) c += __shfl_down(c, o);
        if ((tid & 63) == 0) sRedI[tid >> 6] = c;
        __syncthreads();
        c = sRedI[0] + sRedI[1] + sRedI[2] + sRedI[3];
        if (c >= KFREQ) lo = mid; else hi = mid - 1;
        __syncthreads();
    }
    const unsigned V = lo;

    {
        unsigned m[4] = {um0, um1, um2, um3};
        #pragma unroll
        for (int j = 0; j < 4; ++j) {
            if (m[j] >= V) {
                unsigned pos = atomicAdd(&sKcnt, 1u);
                if (pos < 1024u) { sCand[pos] = tid * 4 + j; sCMag[pos] = __uint_as_float(m[j]); }
            }
        }
        if (xtra >= V) {
            unsigned pos = atomicAdd(&sKcnt, 1u);
            if (pos < 1024u) { sCand[pos] = MM; sCMag[pos] = __uint_as_float(xtra); }
        }
    }
    __syncthreads();

    {
        int kc = (int)min(sKcnt, 1024u);
        for (int j = tid; j < kc; j += TPB) {
            int kb = sCand[j]; float mk = sCMag[j];
            int r = 0;
            for (int i = 0; i < kc; ++i) {
                float mi = sCMag[i]; int bi2 = sCand[i];
                r += (int)((mi > mk) || (mi == mk && bi2 < kb));
            }
            if (r < KFREQ) sScale[kb] = gains[r];
        }
    }
    __syncthreads();

    #pragma unroll
    for (int j = 0; j < 4; ++j) {
        int k = tid + 256 * j;
        float2 Xk = sX[k];      float sk = sScale[k];
        float2 Xp = sX[MM - k]; float sp = sScale[MM - k];
        float Yr = sk * Xk.x,  Yi = sk * Xk.y;
        float Ycr = sp * Xp.x, Yci = -sp * Xp.y;
        float yer = 0.5f * (Yr + Ycr), yei = 0.5f * (Yi + Yci);
        float tr  = 0.5f * (Yr - Ycr), ti  = 0.5f * (Yi - Yci);
        float2 w = tw[MM + k];
        float yor = tr * w.x + ti * w.y;
        float yoi = ti * w.x - tr * w.y;
        sZ[SWZ(BREV10(k))] = make_float2(yer - yoi, yei + yor);
    }

    fft5(sZ, tw, tid, -1.0f);

    float2 zy[4];
    #pragma unroll
    for (int j = 0; j < 4; ++j) zy[j] = sZ[SWZ(4 * tid + j)];

    const float c0 = coeffs[0], c1 = coeffs[1], c2 = coeffs[2];
    const float w1 = mw1[0], b1 = mb1[0], w2 = mw2[0], b2 = mb2[0];
    float tv[8];
    s = 0.f; ss = 0.f;
    #pragma unroll
    for (int j = 0; j < 8; ++j) {
        int d = d0 + j;
        float v = (j & 1) ? zy[j >> 1].y : zy[j >> 1].x;
        float t = v * (1.f / MM) + spec_bias[d];
        float xp = t;
        float acc = c0 * xp;
        xp *= t; acc += c1 * xp;
        xp *= t; acc += c2 * xp;
        float tp = (pmask[d] > 0.f) ? acc : t;
        float y = w1 * tp + b1;
        y = y / (1.f + __expf(-y));
        y = w2 * y + b2;
        y = y / (1.f + __expf(-y));
        float tm = (mmask[d] > 0.f) ? y : tp;
        tv[j] = tm; s += tm; ss += tm * tm;
    }
    blockReduce2(s, ss, sRedF);
    {
        float mu = s * (1.f / DD);
        float var = ss * (1.f / DD) - mu * mu;
        float rstd = rsqrtf(var + 1e-5f);
        bf16x8 o;
        #pragma unroll
        for (int j = 0; j < 8; ++j) {
            int d = d0 + j;
            o[j] = (__bf16)((tv[j] - mu) * rstd * g_out[d] + b_out[d]);
        }
        *(bf16x8*)(hf + (size_t)row * DD + d0) = o;
    }
}

// ---------- GEMM: 256x256 tile, 8-phase pipelined, bf16 MFMA ----------
// out = x + gate*(Hf @ W^T + b_res)
// LDS element (r,c) of a 128x64 half stored at r*64 + (c ^ (((r>>1)&7)<<3));
// staged via linear-dest global_load_lds with pre-swizzled global source.

#define STAGE(G, ROW0, KB, LP) do {                                          \
    _Pragma("unroll")                                                        \
    for (int q_ = 0; q_ < 2; ++q_) {                                         \
        int p_ = (q_ * 512 + tid) * 8;                                       \
        int r_ = p_ >> 6;                                                    \
        int c_ = (p_ & 63) ^ (((r_ >> 1) & 7) << 3);                         \
        gl_lds16((G) + (size_t)((ROW0) + r_) * DD + (KB) + c_, (LP) + p_);   \
    } } while (0)

#define LOADA(BUF, IH) do {                                                  \
    _Pragma("unroll")                                                        \
    for (int ii = 0; ii < 4; ++ii) {                                         \
        int rr = wm * 16 + ii * 32 + l15;                                    \
        int sw = ((rr >> 1) & 7) << 3;                                       \
        aR[ii][0] = *(const bf16x8*)&LA[BUF][IH][rr * 64 + ((l4 * 8) ^ sw)]; \
        aR[ii][1] = *(const bf16x8*)&LA[BUF][IH][rr * 64 + ((32 + l4 * 8) ^ sw)]; \
    } } while (0)

#define LOADB(BUF, JP, DST) do {                                             \
    _Pragma("unroll")                                                        \
    for (int jj = 0; jj < 2; ++jj) {                                         \
        int rr = wn * 16 + jj * 64 + l15;                                    \
        int sw = ((rr >> 1) & 7) << 3;                                       \
        DST[jj][0] = *(const bf16x8*)&LB[BUF][JP][rr * 64 + ((l4 * 8) ^ sw)]; \
        DST[jj][1] = *(const bf16x8*)&LB[BUF][JP][rr * 64 + ((32 + l4 * 8) ^ sw)]; \
    } } while (0)

#define MMAQ(IH, BP, JP) do {                                                \
    _Pragma("unroll")                                                        \
    for (int ii = 0; ii < 4; ++ii) {                                         \
        _Pragma("unroll")                                                    \
        for (int jj = 0; jj < 2; ++jj) {                                     \
            acc[(IH) * 4 + ii][(JP) * 2 + jj] = __builtin_amdgcn_mfma_f32_16x16x32_bf16( \
                aR[ii][0], BP[jj][0], acc[(IH) * 4 + ii][(JP) * 2 + jj], 0, 0, 0);       \
            acc[(IH) * 4 + ii][(JP) * 2 + jj] = __builtin_amdgcn_mfma_f32_16x16x32_bf16( \
                aR[ii][1], BP[jj][1], acc[(IH) * 4 + ii][(JP) * 2 + jj], 0, 0, 0);       \
        }                                                                    \
    } } while (0)

#define PH_PRE() do {                                                        \
    __builtin_amdgcn_sched_barrier(0);                                       \
    __builtin_amdgcn_s_barrier();                                            \
    __builtin_amdgcn_sched_barrier(0);                                       \
    __builtin_amdgcn_s_setprio(1); } while (0)

#define PH_POST() do {                                                       \
    __builtin_amdgcn_s_setprio(0);                                           \
    __builtin_amdgcn_sched_barrier(0);                                       \
    __builtin_amdgcn_s_barrier(); } while (0)

__global__ __launch_bounds__(512, 2) void k_gemm(
    const __bf16* __restrict__ A,   // [8192, 2048] bf16
    const __bf16* __restrict__ Bt,  // [2048, 2048] bf16 (W_res, n-major)
    const float* __restrict__ x,
    const float* __restrict__ b_res,
    const float* __restrict__ gate_p,
    float* __restrict__ out) {

    __shared__ __bf16 LA[2][2][128 * 64];
    __shared__ __bf16 LB[2][2][128 * 64];

    const int tid = threadIdx.x;
    const int lane = tid & 63;
    const int wid = tid >> 6;
    const int wm = wid >> 2;
    const int wn = wid & 3;
    const int l15 = lane & 15;
    const int l4 = lane >> 4;

    // bijective XCD swizzle (nwg = 256, 256 % 8 == 0)
    int orig = blockIdx.y * gridDim.x + blockIdx.x;
    int swz = (orig & 7) * 32 + (orig >> 3);
    const int m0 = (swz >> 3) * 256;
    const int n0 = (swz & 7) * 256;

    f32x4 acc[8][4] = {};
    bf16x8 aR[4][2], bR0[2][2], bR1[2][2];

    // ---- prologue: K0 all, then K1.{A0,B0,A1} ----
    STAGE(A,  m0,       0, &LA[0][0][0]);
    STAGE(Bt, n0,       0, &LB[0][0][0]);
    STAGE(A,  m0 + 128, 0, &LA[0][1][0]);
    STAGE(Bt, n0 + 128, 0, &LB[0][1][0]);
    asm volatile("s_waitcnt vmcnt(4)" ::: "memory");
    STAGE(A,  m0,       BK, &LA[1][0][0]);
    STAGE(Bt, n0,       BK, &LB[1][0][0]);
    STAGE(A,  m0 + 128, BK, &LA[1][1][0]);
    asm volatile("s_waitcnt vmcnt(6)" ::: "memory");
    __builtin_amdgcn_s_barrier();

    for (int T = 0; T < NT; ++T) {
        const int buf = T & 1;
        const int kb1 = (T + 1) * BK;
        const int kb2 = (T + 2) * BK;

        // phase 1: read A-half0 + B-pair0; stage (T+1).B1 -> other buf
        LOADA(buf, 0);
        LOADB(buf, 0, bR0);
        if (T + 1 < NT) STAGE(Bt, n0 + 128, kb1, &LB[buf ^ 1][1][0]);
        PH_PRE();
        MMAQ(0, bR0, 0);
        PH_POST();

        // phase 2: read B-pair1; stage (T+2).A0 -> this buf (half0 free since phase 1)
        LOADB(buf, 1, bR1);
        if (T + 2 < NT) STAGE(A, m0, kb2, &LA[buf][0][0]);
        PH_PRE();
        MMAQ(0, bR1, 1);
        PH_POST();

        // phase 3: read A-half1; stage (T+2).B0 (B-pair0 kept in regs since phase 1)
        LOADA(buf, 1);
        if (T + 2 < NT) STAGE(Bt, n0, kb2, &LB[buf][0][0]);
        PH_PRE();
        MMAQ(1, bR0, 0);
        PH_POST();

        // phase 4: no reads; stage (T+2).A1 (A-half1 last read phase 3, barrier-separated)
        if (T + 2 < NT) STAGE(A, m0 + 128, kb2, &LA[buf][1][0]);
        PH_PRE();
        MMAQ(1, bR1, 1);
        __builtin_amdgcn_s_setprio(0);
        __builtin_amdgcn_sched_barrier(0);
        if (T + 2 < NT) { asm volatile("s_waitcnt vmcnt(6)" ::: "memory"); }
        else            { asm volatile("s_waitcnt vmcnt(0)" ::: "memory"); }
        __builtin_amdgcn_s_barrier();
    }

    // ---- epilogue: out = x + gate*(acc + b_res) ----
    const float gate = gate_p[0];
    #pragma unroll
    for (int i = 0; i < 8; ++i) {
        int rowb = m0 + (i >> 2) * 128 + wm * 16 + (i & 3) * 32 + l4 * 4;
        #pragma unroll
        for (int j = 0; j < 4; ++j) {
            int col = n0 + (j >> 1) * 128 + wn * 16 + (j & 1) * 64 + l15;
            float br = b_res[col];
            #pragma unroll
            for (int r = 0; r < 4; ++r) {
                size_t off = (size_t)(rowb + r) * DD + col;
                out[off] = x[off] + gate * (acc[i][j][r] + br);
            }
        }
    }
}

extern "C" void kernel_launch(void* const* d_in, const int* in_sizes, int n_in,
                              void* d_out, int out_size, void* d_ws, size_t ws_size,
                              hipStream_t stream) {
    const float* x         = (const float*)d_in[0];
    const float* ln_in_g   = (const float*)d_in[1];
    const float* ln_in_b   = (const float*)d_in[2];
    const float* ln_out_g  = (const float*)d_in[3];
    const float* ln_out_b  = (const float*)d_in[4];
    const float* spec_gain = (const float*)d_in[5];
    const float* spec_bias = (const float*)d_in[6];
    const float* poly_c    = (const float*)d_in[7];
    const float* poly_imp  = (const float*)d_in[8];
    const float* micro_imp = (const float*)d_in[9];
    const float* mw1       = (const float*)d_in[10];
    const float* mb1       = (const float*)d_in[11];
    const float* mw2       = (const float*)d_in[12];
    const float* mb2       = (const float*)d_in[13];
    const float* W_res     = (const float*)d_in[14];
    const float* b_res     = (const float*)d_in[15];
    const float* gate      = (const float*)d_in[16];
    float* out = (float*)d_out;

    char* ws = (char*)d_ws;
    __bf16* hf    = (__bf16*)(ws);                       // 32 MiB
    __bf16* Wb    = (__bf16*)(ws + 33554432);            // 8 MiB
    float2* tw    = (float2*)(ws + 41943040);            // 16 KiB
    float*  pmask = (float*)(ws + 41959424);             // 8 KiB
    float*  mmask = (float*)(ws + 41967616);             // 8 KiB

    k_prep<<<dim3(8), dim3(TPB), 0, stream>>>(poly_imp, micro_imp, pmask, mmask, tw);
    k_wcast<<<dim3(2048), dim3(TPB), 0, stream>>>(W_res, Wb);
    k_row<<<dim3(8192), dim3(TPB), 0, stream>>>(x, ln_in_g, ln_in_b, ln_out_g, ln_out_b,
                                                spec_gain, spec_bias, poly_c,
                                                mw1, mb1, mw2, mb2,
                                                pmask, mmask, tw, hf);
    k_gemm<<<dim3(8, 32), dim3(512), 0, stream>>>(hf, Wb, x, b_res, gate, out);
}

// Round 4
// 351.474 us; speedup vs baseline: 2.6720x; 1.4373x over previous
//
#include <hip/hip_runtime.h>
#include <hip/hip_bf16.h>
#include <math.h>

#define DD 2048
#define MM 1024
#define RBINS 1025
#define KFREQ 128
#define TPB 256
#define POLY_KEEP 1024
#define MICRO_KEEP 512
#define BK 64
#define NT (DD / BK)

typedef __bf16 bf16x8 __attribute__((ext_vector_type(8)));
typedef float f32x4 __attribute__((ext_vector_type(4)));
typedef const __attribute__((address_space(1))) void* gas_ptr;
typedef __attribute__((address_space(3))) void* las_ptr;

__device__ __forceinline__ void gl_lds16(const void* g, void* l) {
    __builtin_amdgcn_global_load_lds((gas_ptr)g, (las_ptr)l, 16, 0, 0);
}

__device__ __forceinline__ int SWZ(int i) { return i ^ ((i >> 4) & 15); }
__device__ __forceinline__ int BREV10(int i) { return (int)(__brev((unsigned)i) >> 22); }

// ---------- block reductions (256 threads, 4 waves) ----------
__device__ __forceinline__ void blockReduce2(float& a, float& b, volatile float* sc) {
    for (int o = 32; o; o >>= 1) { a += __shfl_down(a, o); b += __shfl_down(b, o); }
    int w = threadIdx.x >> 6, ln = threadIdx.x & 63;
    if (ln == 0) { sc[w] = a; sc[4 + w] = b; }
    __syncthreads();
    if (threadIdx.x == 0) {
        sc[0] = sc[0] + sc[1] + sc[2] + sc[3];
        sc[4] = sc[4] + sc[5] + sc[6] + sc[7];
    }
    __syncthreads();
    a = sc[0]; b = sc[4];
    __syncthreads();
}

// ---------- in-LDS 1024-pt complex FFT: 5 fused radix-4 stages ----------
__device__ __forceinline__ void fft5(float2* Z, const float2* __restrict__ tw,
                                     int tid, float wsign) {
    #pragma unroll
    for (int s = 0; s < 5; ++s) {
        const int h = 1 << (2 * s);
        __syncthreads();
        int g, p;
        if (s == 1) { g = tid & 63; p = tid >> 6; }
        else { p = tid & (h - 1); g = tid >> (2 * s); }
        const int i0 = g * 4 * h + p;
        float2 T1 = tw[h + p];
        float2 T2 = tw[2 * h + p];
        float2 T3 = tw[3 * h + p];
        const float t1y = wsign * T1.y, t2y = wsign * T2.y, t3y = wsign * T3.y;
        float2 z0 = Z[SWZ(i0)];
        float2 z1 = Z[SWZ(i0 + h)];
        float2 z2 = Z[SWZ(i0 + 2 * h)];
        float2 z3 = Z[SWZ(i0 + 3 * h)];
        float ar = T1.x * z1.x - t1y * z1.y, ai = T1.x * z1.y + t1y * z1.x;
        float br = T1.x * z3.x - t1y * z3.y, bi = T1.x * z3.y + t1y * z3.x;
        float u0r = z0.x + ar, u0i = z0.y + ai;
        float u1r = z0.x - ar, u1i = z0.y - ai;
        float u2r = z2.x + br, u2i = z2.y + bi;
        float u3r = z2.x - br, u3i = z2.y - bi;
        ar = T2.x * u2r - t2y * u2i; ai = T2.x * u2i + t2y * u2r;
        br = T3.x * u3r - t3y * u3i; bi = T3.x * u3i + t3y * u3r;
        Z[SWZ(i0)]         = make_float2(u0r + ar, u0i + ai);
        Z[SWZ(i0 + h)]     = make_float2(u1r + br, u1i + bi);
        Z[SWZ(i0 + 2 * h)] = make_float2(u0r - ar, u0i - ai);
        Z[SWZ(i0 + 3 * h)] = make_float2(u1r - br, u1i - bi);
    }
    __syncthreads();
}

// ---------- setup: masks + twiddles (32 blocks, 4-way split per d) ----------
__global__ __launch_bounds__(TPB) void k_prep(
    const float* __restrict__ poly_imp, const float* __restrict__ micro_imp,
    float* __restrict__ pmask, float* __restrict__ mmask, float2* __restrict__ tw) {
    __shared__ float sP[DD], sM[DD];
    __shared__ int sR[2][TPB];
    const int tid = threadIdx.x;
    for (int i = tid; i < DD; i += TPB) { sP[i] = poly_imp[i]; sM[i] = micro_imp[i]; }
    __syncthreads();
    const int dl = tid >> 2;                 // 0..63
    const int d = blockIdx.x * 64 + dl;
    const int part = tid & 3;
    const float pv = sP[d], mv = sM[d];
    int rp = 0, rm = 0;
    for (int e = part * 512; e < part * 512 + 512; ++e) {
        float pe = sP[e], me = sM[e];
        rp += (int)((pe > pv) || (pe == pv && e < d));
        rm += (int)((me > mv) || (me == mv && e < d));
    }
    sR[0][tid] = rp; sR[1][tid] = rm;
    __syncthreads();
    if (part == 0) {
        int rpt = sR[0][tid] + sR[0][tid + 1] + sR[0][tid + 2] + sR[0][tid + 3];
        int rmt = sR[1][tid] + sR[1][tid + 1] + sR[1][tid + 2] + sR[1][tid + 3];
        pmask[d] = (rpt < POLY_KEEP) ? 1.f : 0.f;
        mmask[d] = (rmt < MICRO_KEEP) ? 1.f : 0.f;
    }
    // twiddles: 64 per block
    if (tid < 64) {
        int i = blockIdx.x * 64 + tid;
        if (i == 0) tw[0] = make_float2(1.f, 0.f);
        else {
            int half = 1 << (31 - __clz(i));
            int p = i - half;
            double ang = M_PI * (double)p / (double)half;
            tw[i] = make_float2((float)cos(ang), (float)(-sin(ang)));
        }
    }
}

// ---------- setup: W_res -> bf16 ----------
__global__ void k_wcast(const float* __restrict__ W, __bf16* __restrict__ Wb) {
    int i = (blockIdx.x * blockDim.x + threadIdx.x) * 8;
    float4 a = *(const float4*)(W + i);
    float4 b = *(const float4*)(W + i + 4);
    bf16x8 o;
    o[0] = (__bf16)a.x; o[1] = (__bf16)a.y; o[2] = (__bf16)a.z; o[3] = (__bf16)a.w;
    o[4] = (__bf16)b.x; o[5] = (__bf16)b.y; o[6] = (__bf16)b.z; o[7] = (__bf16)b.w;
    *(bf16x8*)(Wb + i) = o;
}

// ---------- per-row: LN -> rfft -> topk scale -> irfft -> poly/micro -> LN -> bf16 ----------
__global__ __launch_bounds__(TPB) void k_row(
    const float* __restrict__ x,
    const float* __restrict__ g_in, const float* __restrict__ b_in,
    const float* __restrict__ g_out, const float* __restrict__ b_out,
    const float* __restrict__ gains, const float* __restrict__ spec_bias,
    const float* __restrict__ coeffs,
    const float* __restrict__ mw1, const float* __restrict__ mb1,
    const float* __restrict__ mw2, const float* __restrict__ mb2,
    const float* __restrict__ pmask, const float* __restrict__ mmask,
    const float2* __restrict__ tw,
    __bf16* __restrict__ hf) {

    __shared__ float2 sZ[MM];                 // 8 KB
    __shared__ float sScale[RBINS];           // 4.1 KB
    __shared__ int   sCand[512];              // 2 KB
    __shared__ float sCMag[512];              // 2 KB
    __shared__ unsigned H[264];               // 1 KB hist + 8 group sums
    __shared__ float sRedF[8];
    __shared__ int   sMisc[4];                // [0]=E,[1]=C_above,[2]=Mt
    __shared__ unsigned sKcnt;

    const int tid = threadIdx.x;
    const int row = blockIdx.x;
    const float* xr = x + (size_t)row * DD;
    const int d0 = tid * 8;

    // ---- LN_in ----
    float xv[8];
    {
        float4 a = *(const float4*)(xr + d0);
        float4 b = *(const float4*)(xr + d0 + 4);
        xv[0] = a.x; xv[1] = a.y; xv[2] = a.z; xv[3] = a.w;
        xv[4] = b.x; xv[5] = b.y; xv[6] = b.z; xv[7] = b.w;
    }
    float s = 0.f, ss = 0.f;
    #pragma unroll
    for (int j = 0; j < 8; ++j) { s += xv[j]; ss += xv[j] * xv[j]; }
    blockReduce2(s, ss, sRedF);
    {
        float4 ga = *(const float4*)(g_in + d0);
        float4 gb = *(const float4*)(g_in + d0 + 4);
        float4 ba = *(const float4*)(b_in + d0);
        float4 bb = *(const float4*)(b_in + d0 + 4);
        float gv[8] = {ga.x, ga.y, ga.z, ga.w, gb.x, gb.y, gb.z, gb.w};
        float bv[8] = {ba.x, ba.y, ba.z, ba.w, bb.x, bb.y, bb.z, bb.w};
        float mu = s * (1.f / DD);
        float var = ss * (1.f / DD) - mu * mu;
        float rstd = rsqrtf(var + 1e-5f);
        #pragma unroll
        for (int j = 0; j < 4; ++j) {
            int n = 4 * tid + j;
            float re = (xv[2 * j]     - mu) * rstd * gv[2 * j]     + bv[2 * j];
            float im = (xv[2 * j + 1] - mu) * rstd * gv[2 * j + 1] + bv[2 * j + 1];
            sZ[SWZ(BREV10(n))] = make_float2(re, im);
        }
    }

    fft5(sZ, tw, tid, 1.0f);

    // ---- E0: unpack mags to regs; zero H, sScale, sKcnt ----
    unsigned um[4];
    {
        #pragma unroll
        for (int j = 0; j < 4; ++j) {
            int k = tid + 256 * j;
            float2 a = sZ[SWZ(k)];
            float2 b = sZ[SWZ((MM - k) & (MM - 1))];
            float xer = 0.5f * (a.x + b.x), xei = 0.5f * (a.y - b.y);
            float xor_ = 0.5f * (a.y + b.y), xoi = 0.5f * (b.x - a.x);
            float2 w = tw[MM + k];
            float Xr = xer + w.x * xor_ - w.y * xoi;
            float Xi = xei + w.x * xoi + w.y * xor_;
            um[j] = __float_as_uint(Xr * Xr + Xi * Xi);
        }
    }
    unsigned xtra = 0u;
    if (tid == 0) {
        float2 z0 = sZ[SWZ(0)];
        float xn = z0.x - z0.y;
        xtra = __float_as_uint(xn * xn);
        sKcnt = 0u;
    }
    H[tid] = 0u;
    if (tid < 8) H[256 + tid] = 0u;
    #pragma unroll
    for (int k = tid; k < RBINS; k += TPB) sScale[k] = 0.f;
    __syncthreads();

    // ---- E1: level-1 histogram (exponent byte) ----
    #pragma unroll
    for (int j = 0; j < 4; ++j) atomicAdd(&H[um[j] >> 23], 1u);
    if (tid == 0) atomicAdd(&H[xtra >> 23], 1u);
    __syncthreads();
    // ---- E2: group sums ----
    if (tid < 8) {
        unsigned g = 0;
        for (int i = tid * 32; i < tid * 32 + 32; ++i) g += H[i];
        H[256 + tid] = g;
    }
    __syncthreads();
    // ---- E4: find E = exponent bin of the 128th ----
    {
        int g = tid >> 5;
        unsigned S = 0;
        for (int g2 = g + 1; g2 < 8; ++g2) S += H[256 + g2];
        for (int i = (g + 1) * 32 - 1; i >= tid; --i) S += H[i];
        unsigned U = S - H[tid];
        if (S >= KFREQ && U < KFREQ) { sMisc[0] = tid; sMisc[1] = (int)U; }
    }
    __syncthreads();
    const unsigned E = (unsigned)sMisc[0];
    const unsigned Ca = (unsigned)sMisc[1];
    // ---- E5: zero for level 2 ----
    H[tid] = 0u;
    if (tid < 8) H[256 + tid] = 0u;
    __syncthreads();
    // ---- E6: level-2 histogram (mantissa high byte) among exp==E ----
    #pragma unroll
    for (int j = 0; j < 4; ++j)
        if ((um[j] >> 23) == E) atomicAdd(&H[(um[j] >> 15) & 255], 1u);
    if (tid == 0 && (xtra >> 23) == E) atomicAdd(&H[(xtra >> 15) & 255], 1u);
    __syncthreads();
    // ---- E7: group sums ----
    if (tid < 8) {
        unsigned g = 0;
        for (int i = tid * 32; i < tid * 32 + 32; ++i) g += H[i];
        H[256 + tid] = g;
    }
    __syncthreads();
    // ---- E8: find mantissa bucket ----
    {
        int g = tid >> 5;
        unsigned S = 0;
        for (int g2 = g + 1; g2 < 8; ++g2) S += H[256 + g2];
        for (int i = (g + 1) * 32 - 1; i >= tid; --i) S += H[i];
        unsigned U = S - H[tid];
        if (Ca + S >= KFREQ && Ca + U < KFREQ) sMisc[2] = tid;
    }
    __syncthreads();
    const unsigned T0 = (E << 23) | (((unsigned)sMisc[2]) << 15);

    // ---- E9: compact candidates (bits >= T0; superset of exact top-128) ----
    #pragma unroll
    for (int j = 0; j < 4; ++j) {
        if (um[j] >= T0) {
            unsigned pos = atomicAdd(&sKcnt, 1u);
            if (pos < 512u) { sCand[pos] = tid + 256 * j; sCMag[pos] = __uint_as_float(um[j]); }
        }
    }
    if (tid == 0 && xtra >= T0) {
        unsigned pos = atomicAdd(&sKcnt, 1u);
        if (pos < 512u) { sCand[pos] = MM; sCMag[pos] = __uint_as_float(xtra); }
    }
    __syncthreads();

    // ---- E10: exact ranks among candidates (stable tie-break by index) ----
    {
        int kc = (int)min(sKcnt, 512u);
        for (int j = tid; j < kc; j += TPB) {
            int kb = sCand[j]; float mk = sCMag[j];
            int r = 0;
            for (int i = 0; i < kc; ++i) {
                float mi = sCMag[i]; int bi2 = sCand[i];
                r += (int)((mi > mk) || (mi == mk && bi2 < kb));
            }
            if (r < KFREQ) sScale[kb] = gains[r];
        }
    }
    __syncthreads();

    // ---- E11: pack scaled Hermitian spectrum into regs (recompute X from sZ) ----
    float2 pk[4];
    #pragma unroll
    for (int j = 0; j < 4; ++j) {
        int k = tid + 256 * j;
        float2 a = sZ[SWZ(k)];
        float2 b = sZ[SWZ((MM - k) & (MM - 1))];
        float2 w = tw[MM + k];
        float sk = sScale[k];
        float sp = sScale[(k == 0) ? MM : MM - k];
        // X[k]
        float xer = 0.5f * (a.x + b.x), xei = 0.5f * (a.y - b.y);
        float xor_ = 0.5f * (a.y + b.y), xoi = 0.5f * (b.x - a.x);
        float Xr = xer + w.x * xor_ - w.y * xoi;
        float Xi = xei + w.x * xoi + w.y * xor_;
        // X[MM-k]  (a'=b, b'=a, w' = (-w.x, w.y)); k==0 -> X[1024]
        float X2r, X2i;
        if (k == 0) { X2r = a.x - a.y; X2i = 0.f; }
        else {
            float xer2 = 0.5f * (b.x + a.x), xei2 = 0.5f * (b.y - a.y);
            float xor2 = 0.5f * (b.y + a.y), xoi2 = 0.5f * (a.x - b.x);
            X2r = xer2 - w.x * xor2 - w.y * xoi2;
            X2i = xei2 - w.x * xoi2 + w.y * xor2;
        }
        float Yr = sk * Xr, Yi = sk * Xi;
        float Ycr = sp * X2r, Yci = -sp * X2i;    // conj(Y[MM-k])
        float yer = 0.5f * (Yr + Ycr), yei = 0.5f * (Yi + Yci);
        float tr  = 0.5f * (Yr - Ycr), ti  = 0.5f * (Yi - Yci);
        float yor = tr * w.x + ti * w.y;          // (tr,ti) * conj(w)
        float yoi = ti * w.x - tr * w.y;
        pk[j] = make_float2(yer - yoi, yei + yor);
    }
    __syncthreads();
    // ---- E12: scatter (bit-reversed) ----
    #pragma unroll
    for (int j = 0; j < 4; ++j) {
        int k = tid + 256 * j;
        sZ[SWZ(BREV10(k))] = pk[j];
    }

    fft5(sZ, tw, tid, -1.0f);

    // ---- poly + micro + LN_out, write bf16 ----
    float2 zy[4];
    #pragma unroll
    for (int j = 0; j < 4; ++j) zy[j] = sZ[SWZ(4 * tid + j)];

    const float c0 = coeffs[0], c1 = coeffs[1], c2 = coeffs[2];
    const float w1 = mw1[0], b1 = mb1[0], w2 = mw2[0], b2 = mb2[0];
    float sbv[8], pmv[8], mmv[8];
    {
        float4 a0 = *(const float4*)(spec_bias + d0);
        float4 a1 = *(const float4*)(spec_bias + d0 + 4);
        float4 p0 = *(const float4*)(pmask + d0);
        float4 p1 = *(const float4*)(pmask + d0 + 4);
        float4 m0 = *(const float4*)(mmask + d0);
        float4 m1 = *(const float4*)(mmask + d0 + 4);
        sbv[0]=a0.x; sbv[1]=a0.y; sbv[2]=a0.z; sbv[3]=a0.w; sbv[4]=a1.x; sbv[5]=a1.y; sbv[6]=a1.z; sbv[7]=a1.w;
        pmv[0]=p0.x; pmv[1]=p0.y; pmv[2]=p0.z; pmv[3]=p0.w; pmv[4]=p1.x; pmv[5]=p1.y; pmv[6]=p1.z; pmv[7]=p1.w;
        mmv[0]=m0.x; mmv[1]=m0.y; mmv[2]=m0.z; mmv[3]=m0.w; mmv[4]=m1.x; mmv[5]=m1.y; mmv[6]=m1.z; mmv[7]=m1.w;
    }
    float tv[8];
    s = 0.f; ss = 0.f;
    #pragma unroll
    for (int j = 0; j < 8; ++j) {
        float v = (j & 1) ? zy[j >> 1].y : zy[j >> 1].x;
        float t = v * (1.f / MM) + sbv[j];
        float xp = t;
        float acc = c0 * xp;
        xp *= t; acc += c1 * xp;
        xp *= t; acc += c2 * xp;
        float tp = (pmv[j] > 0.f) ? acc : t;
        float y = w1 * tp + b1;
        y = y / (1.f + __expf(-y));
        y = w2 * y + b2;
        y = y / (1.f + __expf(-y));
        float tm = (mmv[j] > 0.f) ? y : tp;
        tv[j] = tm; s += tm; ss += tm * tm;
    }
    blockReduce2(s, ss, sRedF);
    {
        float4 ga = *(const float4*)(g_out + d0);
        float4 gb = *(const float4*)(g_out + d0 + 4);
        float4 ba = *(const float4*)(b_out + d0);
        float4 bb = *(const float4*)(b_out + d0 + 4);
        float gv[8] = {ga.x, ga.y, ga.z, ga.w, gb.x, gb.y, gb.z, gb.w};
        float bv[8] = {ba.x, ba.y, ba.z, ba.w, bb.x, bb.y, bb.z, bb.w};
        float mu = s * (1.f / DD);
        float var = ss * (1.f / DD) - mu * mu;
        float rstd = rsqrtf(var + 1e-5f);
        bf16x8 o;
        #pragma unroll
        for (int j = 0; j < 8; ++j)
            o[j] = (__bf16)((tv[j] - mu) * rstd * gv[j] + bv[j]);
        *(bf16x8*)(hf + (size_t)row * DD + d0) = o;
    }
}

// ---------- GEMM: 256x256 tile, 8-phase pipelined, bf16 MFMA ----------
// out = x + gate*(Hf @ W^T + b_res)
// LDS element (r,c) of a 128x64 half stored at r*64 + (c ^ (((r>>1)&7)<<3));
// staged via WAVE-UNIFORM-base global_load_lds with pre-swizzled global source.

#define STAGE(G, ROW0, KB, LP) do {                                          \
    _Pragma("unroll")                                                        \
    for (int q_ = 0; q_ < 2; ++q_) {                                         \
        int qb_ = (q_ * 512 + (wid << 6)) * 8;   /* wave-uniform elem base */\
        int pl_ = qb_ + lane * 8;                                            \
        int r_ = pl_ >> 6;                                                   \
        int c_ = (pl_ & 63) ^ (((r_ >> 1) & 7) << 3);                        \
        gl_lds16((G) + (size_t)((ROW0) + r_) * DD + (KB) + c_, (LP) + qb_);  \
    } } while (0)

#define LOADA(BUF, IH) do {                                                  \
    _Pragma("unroll")                                                        \
    for (int ii = 0; ii < 4; ++ii) {                                         \
        int rr = wm * 16 + ii * 32 + l15;                                    \
        int sw = ((rr >> 1) & 7) << 3;                                       \
        aR[ii][0] = *(const bf16x8*)&LA[BUF][IH][rr * 64 + ((l4 * 8) ^ sw)]; \
        aR[ii][1] = *(const bf16x8*)&LA[BUF][IH][rr * 64 + ((32 + l4 * 8) ^ sw)]; \
    } } while (0)

#define LOADB(BUF, JP, DST) do {                                             \
    _Pragma("unroll")                                                        \
    for (int jj = 0; jj < 2; ++jj) {                                         \
        int rr = wn * 16 + jj * 64 + l15;                                    \
        int sw = ((rr >> 1) & 7) << 3;                                       \
        DST[jj][0] = *(const bf16x8*)&LB[BUF][JP][rr * 64 + ((l4 * 8) ^ sw)]; \
        DST[jj][1] = *(const bf16x8*)&LB[BUF][JP][rr * 64 + ((32 + l4 * 8) ^ sw)]; \
    } } while (0)

#define MMAQ(IH, BP, JP) do {                                                \
    _Pragma("unroll")                                                        \
    for (int ii = 0; ii < 4; ++ii) {                                         \
        _Pragma("unroll")                                                    \
        for (int jj = 0; jj < 2; ++jj) {                                     \
            acc[(IH) * 4 + ii][(JP) * 2 + jj] = __builtin_amdgcn_mfma_f32_16x16x32_bf16( \
                aR[ii][0], BP[jj][0], acc[(IH) * 4 + ii][(JP) * 2 + jj], 0, 0, 0);       \
            acc[(IH) * 4 + ii][(JP) * 2 + jj] = __builtin_amdgcn_mfma_f32_16x16x32_bf16( \
                aR[ii][1], BP[jj][1], acc[(IH) * 4 + ii][(JP) * 2 + jj], 0, 0, 0);       \
        }                                                                    \
    } } while (0)

#define PH_PRE() do {                                                        \
    __builtin_amdgcn_sched_barrier(0);                                       \
    __builtin_amdgcn_s_barrier();                                            \
    __builtin_amdgcn_sched_barrier(0);                                       \
    __builtin_amdgcn_s_setprio(1); } while (0)

#define PH_POST() do {                                                       \
    __builtin_amdgcn_s_setprio(0);                                           \
    __builtin_amdgcn_sched_barrier(0);                                       \
    __builtin_amdgcn_s_barrier(); } while (0)

__global__ __launch_bounds__(512, 2) void k_gemm(
    const __bf16* __restrict__ A,   // [8192, 2048] bf16
    const __bf16* __restrict__ Bt,  // [2048, 2048] bf16 (W_res, n-major)
    const float* __restrict__ x,
    const float* __restrict__ b_res,
    const float* __restrict__ gate_p,
    float* __restrict__ out) {

    __shared__ __bf16 LA[2][2][128 * 64];
    __shared__ __bf16 LB[2][2][128 * 64];

    const int tid = threadIdx.x;
    const int lane = tid & 63;
    const int wid = tid >> 6;
    const int wm = wid >> 2;
    const int wn = wid & 3;
    const int l15 = lane & 15;
    const int l4 = lane >> 4;

    // bijective XCD swizzle (nwg = 256, 256 % 8 == 0)
    int orig = blockIdx.y * gridDim.x + blockIdx.x;
    int swz = (orig & 7) * 32 + (orig >> 3);
    const int m0 = (swz >> 3) * 256;
    const int n0 = (swz & 7) * 256;

    f32x4 acc[8][4] = {};
    bf16x8 aR[4][2], bR0[2][2], bR1[2][2];

    // ---- prologue: K0 all, then K1.{A0,B0,A1} ----
    STAGE(A,  m0,       0, &LA[0][0][0]);
    STAGE(Bt, n0,       0, &LB[0][0][0]);
    STAGE(A,  m0 + 128, 0, &LA[0][1][0]);
    STAGE(Bt, n0 + 128, 0, &LB[0][1][0]);
    asm volatile("s_waitcnt vmcnt(4)" ::: "memory");
    STAGE(A,  m0,       BK, &LA[1][0][0]);
    STAGE(Bt, n0,       BK, &LB[1][0][0]);
    STAGE(A,  m0 + 128, BK, &LA[1][1][0]);
    asm volatile("s_waitcnt vmcnt(6)" ::: "memory");
    __builtin_amdgcn_s_barrier();

    for (int T = 0; T < NT; ++T) {
        const int buf = T & 1;
        const int kb1 = (T + 1) * BK;
        const int kb2 = (T + 2) * BK;

        // phase 1: read A-half0 + B-pair0; stage (T+1).B1 -> other buf
        LOADA(buf, 0);
        LOADB(buf, 0, bR0);
        if (T + 1 < NT) STAGE(Bt, n0 + 128, kb1, &LB[buf ^ 1][1][0]);
        PH_PRE();
        MMAQ(0, bR0, 0);
        PH_POST();

        // phase 2: read B-pair1; stage (T+2).A0 -> this buf
        LOADB(buf, 1, bR1);
        if (T + 2 < NT) STAGE(A, m0, kb2, &LA[buf][0][0]);
        PH_PRE();
        MMAQ(0, bR1, 1);
        PH_POST();

        // phase 3: read A-half1; stage (T+2).B0
        LOADA(buf, 1);
        if (T + 2 < NT) STAGE(Bt, n0, kb2, &LB[buf][0][0]);
        PH_PRE();
        MMAQ(1, bR0, 0);
        PH_POST();

        // phase 4: no reads; stage (T+2).A1
        if (T + 2 < NT) STAGE(A, m0 + 128, kb2, &LA[buf][1][0]);
        PH_PRE();
        MMAQ(1, bR1, 1);
        __builtin_amdgcn_s_setprio(0);
        __builtin_amdgcn_sched_barrier(0);
        if (T + 2 < NT) { asm volatile("s_waitcnt vmcnt(6)" ::: "memory"); }
        else            { asm volatile("s_waitcnt vmcnt(0)" ::: "memory"); }
        __builtin_amdgcn_s_barrier();
    }

    // ---- epilogue: out = x + gate*(acc + b_res) ----
    const float gate = gate_p[0];
    #pragma unroll
    for (int i = 0; i < 8; ++i) {
        int rowb = m0 + (i >> 2) * 128 + wm * 16 + (i & 3) * 32 + l4 * 4;
        #pragma unroll
        for (int j = 0; j < 4; ++j) {
            int col = n0 + (j >> 1) * 128 + wn * 16 + (j & 1) * 64 + l15;
            float br = b_res[col];
            #pragma unroll
            for (int r = 0; r < 4; ++r) {
                size_t off = (size_t)(rowb + r) * DD + col;
                out[off] = x[off] + gate * (acc[i][j][r] + br);
            }
        }
    }
}

extern "C" void kernel_launch(void* const* d_in, const int* in_sizes, int n_in,
                              void* d_out, int out_size, void* d_ws, size_t ws_size,
                              hipStream_t stream) {
    const float* x         = (const float*)d_in[0];
    const float* ln_in_g   = (const float*)d_in[1];
    const float* ln_in_b   = (const float*)d_in[2];
    const float* ln_out_g  = (const float*)d_in[3];
    const float* ln_out_b  = (const float*)d_in[4];
    const float* spec_gain = (const float*)d_in[5];
    const float* spec_bias = (const float*)d_in[6];
    const float* poly_c    = (const float*)d_in[7];
    const float* poly_imp  = (const float*)d_in[8];
    const float* micro_imp = (const float*)d_in[9];
    const float* mw1       = (const float*)d_in[10];
    const float* mb1       = (const float*)d_in[11];
    const float* mw2       = (const float*)d_in[12];
    const float* mb2       = (const float*)d_in[13];
    const float* W_res     = (const float*)d_in[14];
    const float* b_res     = (const float*)d_in[15];
    const float* gate      = (const float*)d_in[16];
    float* out = (float*)d_out;

    char* ws = (char*)d_ws;
    __bf16* hf    = (__bf16*)(ws);                       // 32 MiB
    __bf16* Wb    = (__bf16*)(ws + 33554432);            // 8 MiB
    float2* tw    = (float2*)(ws + 41943040);            // 16 KiB
    float*  pmask = (float*)(ws + 41959424);             // 8 KiB
    float*  mmask = (float*)(ws + 41967616);             // 8 KiB

    k_prep<<<dim3(32), dim3(TPB), 0, stream>>>(poly_imp, micro_imp, pmask, mmask, tw);
    k_wcast<<<dim3(2048), dim3(TPB), 0, stream>>>(W_res, Wb);
    k_row<<<dim3(8192), dim3(TPB), 0, stream>>>(x, ln_in_g, ln_in_b, ln_out_g, ln_out_b,
                                                spec_gain, spec_bias, poly_c,
                                                mw1, mb1, mw2, mb2,
                                                pmask, mmask, tw, hf);
    k_gemm<<<dim3(8, 32), dim3(512), 0, stream>>>(hf, Wb, x, b_res, gate, out);
}